// Round 1
// baseline (68.111 us; speedup 1.0000x reference)
//
#include <hip/hip_runtime.h>
#include <stdint.h>

#define N_TOTAL 4096
#define DIMS 256
#define M_HALF 2048
#define NNEIGH 30

typedef __bf16 bf16_t;
typedef bf16_t bf16x8 __attribute__((ext_vector_type(8)));
typedef float f32x4 __attribute__((ext_vector_type(4)));

__device__ inline uint16_t f2bf(float f) {
    union { float f; uint32_t u; } v; v.f = f;
    uint32_t u = v.u;
    uint32_t r = (u + 0x7fffu + ((u >> 16) & 1u)) >> 16;  // RNE
    return (uint16_t)r;
}

// Normalize + transpose: emb[16][256 d][256 l] f32  ->  F[4096 r][256 d] bf16
// r = bi*256 + l ; F[r][d] = emb[bi][d][l] / ||emb[bi][:][l]||
__global__ __launch_bounds__(256) void nt_kernel(const float* __restrict__ emb,
                                                 uint16_t* __restrict__ F) {
    __shared__ float tile[16][257];
    __shared__ float invn[16];
    const int bi = blockIdx.x >> 4;
    const int lc = blockIdx.x & 15;
    const int l0 = lc * 16;
    const int tid = threadIdx.x;
    const float* src = emb + (size_t)bi * DIMS * 256 + l0;
    // load 16(l) x 256(d) tile, coalesced along l
    #pragma unroll
    for (int p = 0; p < 16; ++p) {
        int idx = p * 256 + tid;
        int l = idx & 15;
        int d = idx >> 4;
        tile[l][d] = src[(size_t)d * 256 + l];
    }
    __syncthreads();
    // norms: 16 threads per row l
    {
        int l = tid >> 4;
        int c = tid & 15;
        float ss = 0.f;
        #pragma unroll
        for (int d = 0; d < 256; d += 16) {
            float v = tile[l][d + c];
            ss += v * v;
        }
        ss += __shfl_xor(ss, 1, 64);
        ss += __shfl_xor(ss, 2, 64);
        ss += __shfl_xor(ss, 4, 64);
        ss += __shfl_xor(ss, 8, 64);
        if (c == 0) invn[l] = 1.0f / fmaxf(sqrtf(ss), 1e-12f);
    }
    __syncthreads();
    // write transposed + normalized, coalesced along d
    #pragma unroll
    for (int p = 0; p < 16; ++p) {
        int r = bi * 256 + l0 + p;
        F[(size_t)r * DIMS + tid] = f2bf(tile[p][tid] * invn[p]);
    }
}

// One wave computes a 64x64 tile of sims = F * F^T, then fused epilogue:
// e = exp(sim/T)*w(col-row); row-partial sums atomically into den[row];
// the single partner element per row stored to num[row].
__global__ __launch_bounds__(256) void sim_kernel(const uint16_t* __restrict__ F,
                                                  float* __restrict__ den,
                                                  float* __restrict__ num) {
    const int wid = blockIdx.x * 4 + (threadIdx.x >> 6);
    const int lane = threadIdx.x & 63;
    const int ti = wid >> 6, tj = wid & 63;
    const int i0 = ti * 64, j0 = tj * 64;
    const int lr = lane & 15;   // A row / B col / C col
    const int kg = lane >> 4;   // k-group

    f32x4 acc[4][4];
    #pragma unroll
    for (int a = 0; a < 4; ++a)
        #pragma unroll
        for (int b = 0; b < 4; ++b) acc[a][b] = (f32x4){0.f, 0.f, 0.f, 0.f};

    const bf16x8* Fv = reinterpret_cast<const bf16x8*>(F);  // row = 32 vectors
    #pragma unroll
    for (int k0 = 0; k0 < DIMS; k0 += 32) {
        const int kb = (k0 >> 3) + kg;
        bf16x8 af[4], bfr[4];
        #pragma unroll
        for (int a = 0; a < 4; ++a) af[a]  = Fv[(size_t)(i0 + a * 16 + lr) * 32 + kb];
        #pragma unroll
        for (int b = 0; b < 4; ++b) bfr[b] = Fv[(size_t)(j0 + b * 16 + lr) * 32 + kb];
        #pragma unroll
        for (int a = 0; a < 4; ++a)
            #pragma unroll
            for (int b = 0; b < 4; ++b)
                acc[a][b] = __builtin_amdgcn_mfma_f32_16x16x32_bf16(af[a], bfr[b], acc[a][b], 0, 0, 0);
    }

    const float invT = 1.0f / 0.07f;
    const float slope = 1.0f / (float)NNEIGH;
    float rs[4][4];
    #pragma unroll
    for (int a = 0; a < 4; ++a)
        #pragma unroll
        for (int e = 0; e < 4; ++e) rs[a][e] = 0.f;

    #pragma unroll
    for (int a = 0; a < 4; ++a) {
        #pragma unroll
        for (int b = 0; b < 4; ++b) {
            const int col = j0 + b * 16 + lr;
            #pragma unroll
            for (int e = 0; e < 4; ++e) {
                const int row = i0 + a * 16 + kg * 4 + e;
                const int d = col - row;
                float wv = (d >= 0) ? fminf((float)d * slope, 1.0f)
                                    : ((d >= -NNEIGH) ? (float)(-d - 1) * slope : 1.0f);
                float v = __expf(acc[a][b][e] * invT) * wv;
                rs[a][e] += v;
                int pc = row + M_HALF;
                if (pc >= N_TOTAL) pc -= N_TOTAL;
                if (col == pc) num[row] = v;
            }
        }
    }
    // reduce the 16 lanes of each k-group (they hold the 16 cols of a sub-tile)
    #pragma unroll
    for (int a = 0; a < 4; ++a)
        #pragma unroll
        for (int e = 0; e < 4; ++e) {
            float s = rs[a][e];
            s += __shfl_xor(s, 1, 64);
            s += __shfl_xor(s, 2, 64);
            s += __shfl_xor(s, 4, 64);
            s += __shfl_xor(s, 8, 64);
            if (lr == 0) atomicAdd(&den[i0 + a * 16 + kg * 4 + e], s);
        }
}

__global__ __launch_bounds__(256) void fin_kernel(const float* __restrict__ num,
                                                  const float* __restrict__ den,
                                                  float* __restrict__ out) {
    __shared__ float sbuf[4];
    const int tid = threadIdx.x;
    float s = 0.f;
    for (int i = tid; i < N_TOTAL; i += 256) s += num[i] / den[i];
    s += __shfl_xor(s, 1, 64);
    s += __shfl_xor(s, 2, 64);
    s += __shfl_xor(s, 4, 64);
    s += __shfl_xor(s, 8, 64);
    s += __shfl_xor(s, 16, 64);
    s += __shfl_xor(s, 32, 64);
    if ((tid & 63) == 0) sbuf[tid >> 6] = s;
    __syncthreads();
    if (tid == 0) out[0] = (sbuf[0] + sbuf[1] + sbuf[2] + sbuf[3]) * (1.0f / (float)N_TOTAL);
}

extern "C" void kernel_launch(void* const* d_in, const int* in_sizes, int n_in,
                              void* d_out, int out_size, void* d_ws, size_t ws_size,
                              hipStream_t stream) {
    const float* emb = (const float*)d_in[0];
    // masks (d_in[1]) and labelvecs (d_in[2]) are unused by the reference output
    uint16_t* F = (uint16_t*)d_ws;
    float* den = (float*)((char*)d_ws + (size_t)N_TOTAL * DIMS * sizeof(uint16_t));
    float* num = den + N_TOTAL;

    hipMemsetAsync(den, 0, N_TOTAL * sizeof(float), stream);
    nt_kernel<<<dim3(256), dim3(256), 0, stream>>>(emb, F);
    sim_kernel<<<dim3((N_TOTAL / 64) * (N_TOTAL / 64) / 4), dim3(256), 0, stream>>>(F, den, num);
    fin_kernel<<<dim3(1), dim3(256), 0, stream>>>(num, den, (float*)d_out);
}

// Round 2
// 44.008 us; speedup vs baseline: 1.5477x; 1.5477x over previous
//
#include <hip/hip_runtime.h>
#include <stdint.h>

#define N_TOTAL 4096
#define DIMS 256
#define M_HALF 2048
#define NNEIGH 30

typedef __bf16 bf16_t;
typedef bf16_t bf16x8 __attribute__((ext_vector_type(8)));
typedef float f32x4 __attribute__((ext_vector_type(4)));

typedef __attribute__((address_space(3))) uint32_t lds_u32;
typedef const __attribute__((address_space(1))) uint32_t glb_u32;

__device__ inline uint16_t f2bf(float f) {
    union { float f; uint32_t u; } v; v.f = f;
    uint32_t u = v.u;
    uint32_t r = (u + 0x7fffu + ((u >> 16) & 1u)) >> 16;  // RNE
    return (uint16_t)r;
}

// Normalize + transpose: emb[16][256 d][256 l] f32  ->  F[4096 r][256 d] bf16
// r = bi*256 + l ; F[r][d] = emb[bi][d][l] / ||emb[bi][:][l]||
// Also zeroes den[] (folded former memset).
__global__ __launch_bounds__(256) void nt_kernel(const float* __restrict__ emb,
                                                 uint16_t* __restrict__ F,
                                                 float* __restrict__ den) {
    __shared__ float tile[16][257];
    __shared__ float invn[16];
    const int bi = blockIdx.x >> 4;
    const int lc = blockIdx.x & 15;
    const int l0 = lc * 16;
    const int tid = threadIdx.x;
    if (tid < 16) den[blockIdx.x * 16 + tid] = 0.f;
    const float* src = emb + (size_t)bi * DIMS * 256 + l0;
    #pragma unroll
    for (int p = 0; p < 16; ++p) {
        int idx = p * 256 + tid;
        int l = idx & 15;
        int d = idx >> 4;
        tile[l][d] = src[(size_t)d * 256 + l];
    }
    __syncthreads();
    {
        int l = tid >> 4;
        int c = tid & 15;
        float ss = 0.f;
        #pragma unroll
        for (int d = 0; d < 256; d += 16) {
            float v = tile[l][d + c];
            ss += v * v;
        }
        ss += __shfl_xor(ss, 1, 64);
        ss += __shfl_xor(ss, 2, 64);
        ss += __shfl_xor(ss, 4, 64);
        ss += __shfl_xor(ss, 8, 64);
        if (c == 0) invn[l] = 1.0f / fmaxf(sqrtf(ss), 1e-12f);
    }
    __syncthreads();
    #pragma unroll
    for (int p = 0; p < 16; ++p) {
        int r = bi * 256 + l0 + p;
        F[(size_t)r * DIMS + tid] = f2bf(tile[p][tid] * invn[p]);
    }
}

// Stage one 128x64 bf16 panel pair (A rows rowA0.., B rows rowB0.., k-cols k0..k0+63)
// into LDS buffer `buf`. LDS dest is linear (global_load_lds requirement);
// the st-16x32-style XOR swizzle is applied by permuting the GLOBAL source
// chunk (rule #21: inverse-swizzled source + swizzled read).
__device__ inline void stage_tile(const uint16_t* __restrict__ F, char* smem,
                                  int buf, int k0, int rowA0, int rowB0, int tid) {
    const int wid = tid >> 6;
    #pragma unroll
    for (int i = 0; i < 4; ++i) {
        int p = i * 256 + tid;          // 16B-chunk index within 16KB panel
        int row = p >> 3;               // 8 chunks (128B) per row
        int pc = p & 7;                 // physical chunk in row
        int c = pc ^ (row & 7);         // logical k-chunk stored here
        const uint16_t* ga = F + (size_t)(rowA0 + row) * DIMS + k0 + c * 8;
        char* la = smem + buf * 32768 + i * 4096 + wid * 1024;  // wave-uniform base
        __builtin_amdgcn_global_load_lds((glb_u32*)ga, (lds_u32*)la, 16, 0, 0);
    }
    #pragma unroll
    for (int i = 0; i < 4; ++i) {
        int p = i * 256 + tid;
        int row = p >> 3;
        int pc = p & 7;
        int c = pc ^ (row & 7);
        const uint16_t* gb = F + (size_t)(rowB0 + row) * DIMS + k0 + c * 8;
        char* lb = smem + buf * 32768 + 16384 + i * 4096 + wid * 1024;
        __builtin_amdgcn_global_load_lds((glb_u32*)gb, (lds_u32*)lb, 16, 0, 0);
    }
}

// Block computes a 128x128 tile of sims = F * F^T (4 waves, 2x2 quadrants of 64x64),
// LDS-staged, double-buffered, then fused exp/weight epilogue.
__global__ __launch_bounds__(256) void sim_kernel(const uint16_t* __restrict__ F,
                                                  float* __restrict__ den,
                                                  float* __restrict__ num) {
    __shared__ char smem[65536];
    const int tid = threadIdx.x;
    const int wid = tid >> 6;
    const int lane = tid & 63;
    const int lr = lane & 15;
    const int kg = lane >> 4;
    const int wr = wid >> 1, wc = wid & 1;

    // XCD-aware swizzle: 1024 blocks, 8 XCDs -> XCD x owns ti in [x*4, x*4+4)
    const int bid = blockIdx.x;
    const int swz = (bid & 7) * 128 + (bid >> 3);
    const int bm = swz >> 5, bn = swz & 31;
    const int rowA0 = bm * 128, rowB0 = bn * 128;

    f32x4 acc[4][4];
    #pragma unroll
    for (int a = 0; a < 4; ++a)
        #pragma unroll
        for (int b = 0; b < 4; ++b) acc[a][b] = (f32x4){0.f, 0.f, 0.f, 0.f};

    stage_tile(F, smem, 0, 0, rowA0, rowB0, tid);
    __syncthreads();  // compiler emits vmcnt(0) before s_barrier

    for (int t = 0; t < 4; ++t) {
        const int cur = t & 1;
        if (t < 3) stage_tile(F, smem, cur ^ 1, (t + 1) * 64, rowA0, rowB0, tid);
        const char* Ab = smem + cur * 32768;
        const char* Bb = Ab + 16384;
        #pragma unroll
        for (int kk = 0; kk < 2; ++kk) {
            bf16x8 af[4], bfr[4];
            #pragma unroll
            for (int a = 0; a < 4; ++a) {
                int r = wr * 64 + a * 16 + lr;
                int pc = (kk * 4 + kg) ^ (r & 7);
                af[a] = *(const bf16x8*)(Ab + r * 128 + pc * 16);
            }
            #pragma unroll
            for (int b = 0; b < 4; ++b) {
                int r = wc * 64 + b * 16 + lr;
                int pc = (kk * 4 + kg) ^ (r & 7);
                bfr[b] = *(const bf16x8*)(Bb + r * 128 + pc * 16);
            }
            #pragma unroll
            for (int a = 0; a < 4; ++a)
                #pragma unroll
                for (int b = 0; b < 4; ++b)
                    acc[a][b] = __builtin_amdgcn_mfma_f32_16x16x32_bf16(af[a], bfr[b], acc[a][b], 0, 0, 0);
        }
        __syncthreads();
    }

    const int i0 = rowA0 + wr * 64;
    const int j0 = rowB0 + wc * 64;
    const float invT = 1.0f / 0.07f;
    const float slope = 1.0f / (float)NNEIGH;
    float rs[4][4];
    #pragma unroll
    for (int a = 0; a < 4; ++a)
        #pragma unroll
        for (int e = 0; e < 4; ++e) rs[a][e] = 0.f;

    #pragma unroll
    for (int a = 0; a < 4; ++a) {
        #pragma unroll
        for (int b = 0; b < 4; ++b) {
            const int col = j0 + b * 16 + lr;
            #pragma unroll
            for (int e = 0; e < 4; ++e) {
                const int row = i0 + a * 16 + kg * 4 + e;
                const int d = col - row;
                float wv = (d >= 0) ? fminf((float)d * slope, 1.0f)
                                    : ((d >= -NNEIGH) ? (float)(-d - 1) * slope : 1.0f);
                float v = __expf(acc[a][b][e] * invT) * wv;
                rs[a][e] += v;
                int pc = row + M_HALF;
                if (pc >= N_TOTAL) pc -= N_TOTAL;
                if (col == pc) num[row] = v;
            }
        }
    }
    #pragma unroll
    for (int a = 0; a < 4; ++a)
        #pragma unroll
        for (int e = 0; e < 4; ++e) {
            float s = rs[a][e];
            s += __shfl_xor(s, 1, 64);
            s += __shfl_xor(s, 2, 64);
            s += __shfl_xor(s, 4, 64);
            s += __shfl_xor(s, 8, 64);
            if (lr == 0) atomicAdd(&den[i0 + a * 16 + kg * 4 + e], s);
        }
}

__global__ __launch_bounds__(256) void fin_kernel(const float* __restrict__ num,
                                                  const float* __restrict__ den,
                                                  float* __restrict__ out) {
    __shared__ float sbuf[4];
    const int tid = threadIdx.x;
    float s = 0.f;
    for (int i = tid; i < N_TOTAL; i += 256) s += num[i] / den[i];
    s += __shfl_xor(s, 1, 64);
    s += __shfl_xor(s, 2, 64);
    s += __shfl_xor(s, 4, 64);
    s += __shfl_xor(s, 8, 64);
    s += __shfl_xor(s, 16, 64);
    s += __shfl_xor(s, 32, 64);
    if ((tid & 63) == 0) sbuf[tid >> 6] = s;
    __syncthreads();
    if (tid == 0) out[0] = (sbuf[0] + sbuf[1] + sbuf[2] + sbuf[3]) * (1.0f / (float)N_TOTAL);
}

extern "C" void kernel_launch(void* const* d_in, const int* in_sizes, int n_in,
                              void* d_out, int out_size, void* d_ws, size_t ws_size,
                              hipStream_t stream) {
    const float* emb = (const float*)d_in[0];
    // masks (d_in[1]) and labelvecs (d_in[2]) are unused by the reference output
    uint16_t* F = (uint16_t*)d_ws;
    float* den = (float*)((char*)d_ws + (size_t)N_TOTAL * DIMS * sizeof(uint16_t));
    float* num = den + N_TOTAL;

    nt_kernel<<<dim3(256), dim3(256), 0, stream>>>(emb, F, den);
    sim_kernel<<<dim3(1024), dim3(256), 0, stream>>>(F, den, num);
    fin_kernel<<<dim3(1), dim3(256), 0, stream>>>(num, den, (float*)d_out);
}